// Round 7
// baseline (442.112 us; speedup 1.0000x reference)
//
#include <hip/hip_runtime.h>
#include <hip/hip_fp16.h>

// Net_55439437857087: per-pixel MLP 2->8->4x(8x8)->3 over 16.7M pixels.
// LUT arc (R3-R10): 512x512 vertical-pair table + bilinear, 2MB, 151us main.
//   R6: request count irrelevant. R7: line count is the lever. R9: A(2x8B)=
//   B(1x16B)=C(NT 16B) -> not L1-allocate overhead. R10: ILP pipeline
//   REGRESSED (occ 78->64, LLC x-retention broken, FETCH +38MB). Model:
//   ~18.8M line-misses x ~250cy L2 latency / ~64 outstanding per CU ~= 140us
//   => MSHR-parallelism bound. LUT floor ~150us main. Fixed harness fills
//   ~232us; main kernel is the only lever.
// R11 (this round): half/half A/B. First half: direct2 (exact fp32 MLP,
//   2px/thread interleaved chains, weights in registers via static-index
//   local arrays). Issue-bound estimate 3.5 cy/px/CU (~97us full range) vs
//   LUT's measured 5.5. Old R2 direct (250us) was 2.5x its issue bound =
//   codegen stalls, retrying with explicit ILP. Second half: proven R9-B
//   LUT sampler (bit-identical, keeps absmax 0.00390625).

#define EXP2F(x) __builtin_amdgcn_exp2f(x)
#define RCPF(x)  __builtin_amdgcn_rcpf(x)

#define G 512
#define GM1F 511.0f

typedef float vfloat4 __attribute__((ext_vector_type(4)));  // nontemporal-compatible
typedef float vfloat2 __attribute__((ext_vector_type(2)));
typedef unsigned int uv4 __attribute__((ext_vector_type(4), aligned(8)));

// ---- single-pixel network eval (build passes + fallback) ----
__device__ __forceinline__ void net_eval(
    float px, float py,
    const float* __restrict__ Win, const float* __restrict__ Wh,
    const float* __restrict__ Wout, float o[3])
{
    const float S  = 2.8853900817779268f;   // 2*log2(e)
    const float SO = -1.4426950408889634f;  // -log2(e)
    float h[8];
#pragma unroll
    for (int j = 0; j < 8; ++j) {
        float acc = __builtin_fmaf(px, Win[2 * j], py * Win[2 * j + 1]);
        h[j] = __builtin_fmaf(-2.0f, RCPF(EXP2F(S * acc) + 1.0f), 1.0f);
    }
#pragma unroll
    for (int L = 0; L < 4; ++L) {
        float nh[8];
#pragma unroll
        for (int j = 0; j < 8; ++j) {
            float acc = 0.0f;
#pragma unroll
            for (int k = 0; k < 8; ++k)
                acc = __builtin_fmaf(h[k], Wh[8 * j + k], acc);
            nh[j] = __builtin_fmaf(-2.0f, RCPF(EXP2F(S * acc) + 1.0f), 1.0f);
        }
#pragma unroll
        for (int j = 0; j < 8; ++j) h[j] = nh[j];
    }
#pragma unroll
    for (int c = 0; c < 3; ++c) {
        float acc = 0.0f;
#pragma unroll
        for (int k = 0; k < 8; ++k)
            acc = __builtin_fmaf(h[k], Wout[8 * c + k], acc);
        o[c] = RCPF(EXP2F(SO * acc) + 1.0f);
    }
}

// ---- two-pixel interleaved eval (explicit ILP; weights pre-cached) ----
__device__ __forceinline__ void eval2(
    float px0, float py0, float px1, float py1,
    const float* __restrict__ win, const float* __restrict__ wh,
    const float* __restrict__ wo, float o0[3], float o1[3])
{
    const float S  = 2.8853900817779268f;   // 2*log2(e)
    const float SO = -1.4426950408889634f;  // -log2(e)
    float h0[8], h1[8];
#pragma unroll
    for (int j = 0; j < 8; ++j) {
        float a0 = __builtin_fmaf(px0, win[2 * j], py0 * win[2 * j + 1]);
        float a1 = __builtin_fmaf(px1, win[2 * j], py1 * win[2 * j + 1]);
        h0[j] = __builtin_fmaf(-2.0f, RCPF(EXP2F(S * a0) + 1.0f), 1.0f);
        h1[j] = __builtin_fmaf(-2.0f, RCPF(EXP2F(S * a1) + 1.0f), 1.0f);
    }
#pragma unroll
    for (int L = 0; L < 4; ++L) {
        float n0[8], n1[8];
#pragma unroll
        for (int j = 0; j < 8; ++j) {
            float a0 = 0.0f, a1 = 0.0f;
#pragma unroll
            for (int k = 0; k < 8; ++k) {
                a0 = __builtin_fmaf(h0[k], wh[8 * j + k], a0);
                a1 = __builtin_fmaf(h1[k], wh[8 * j + k], a1);
            }
            n0[j] = __builtin_fmaf(-2.0f, RCPF(EXP2F(S * a0) + 1.0f), 1.0f);
            n1[j] = __builtin_fmaf(-2.0f, RCPF(EXP2F(S * a1) + 1.0f), 1.0f);
        }
#pragma unroll
        for (int j = 0; j < 8; ++j) { h0[j] = n0[j]; h1[j] = n1[j]; }
    }
#pragma unroll
    for (int c = 0; c < 3; ++c) {
        float a0 = 0.0f, a1 = 0.0f;
#pragma unroll
        for (int k = 0; k < 8; ++k) {
            a0 = __builtin_fmaf(h0[k], wo[8 * c + k], a0);
            a1 = __builtin_fmaf(h1[k], wo[8 * c + k], a1);
        }
        o0[c] = RCPF(EXP2F(SO * a0) + 1.0f);
        o1[c] = RCPF(EXP2F(SO * a1) + 1.0f);
    }
}

// ================= build passes (unchanged) =================

__global__ __launch_bounds__(256) void build_tex_kernel(
    const float* __restrict__ Win, const float* __restrict__ Wh,
    const float* __restrict__ Wout, unsigned int* __restrict__ tex)
{
    int t = blockIdx.x * blockDim.x + threadIdx.x;
    if (t >= G * G) return;
    int i = t & (G - 1);
    int j = t >> 9;               // t / G
    const float inv = 1.0f / GM1F;
    float o[3];
    net_eval(i * inv, j * inv, Win, Wh, Wout, o);
    unsigned int r = (unsigned int)__builtin_rintf(o[0] * 2047.0f);
    unsigned int g = (unsigned int)__builtin_rintf(o[1] * 2047.0f);
    unsigned int b = (unsigned int)__builtin_rintf(o[2] * 1023.0f);
    tex[t] = r | (g << 11) | (b << 22);
}

// Entry (ix,iy): texel(ix,iy) in .x, texel(ix,iy+1) in .y  (vertical pair)
__global__ __launch_bounds__(256) void build_vpair_kernel(
    const unsigned int* __restrict__ tex, uint2* __restrict__ pair)
{
    int t = blockIdx.x * blockDim.x + threadIdx.x;
    if (t >= G * G) return;
    int ix = t & (G - 1);
    int iy = t >> 9;
    int iy1 = min(iy + 1, G - 1);
    uint2 q;
    q.x = tex[iy * G + ix];
    q.y = tex[iy1 * G + ix];
    pair[t] = q;
}

// ================= LUT sampling (bit-identical to R9-B) =================

__device__ __forceinline__ float3 unpack_raw(unsigned int v) {
    return make_float3((float)(v & 2047u),
                       (float)((v >> 11) & 2047u),
                       (float)(v >> 22));
}

__device__ __forceinline__ float3 lerp3(float3 a, float3 b, float t) {
    return make_float3(__builtin_fmaf(t, b.x - a.x, a.x),
                       __builtin_fmaf(t, b.y - a.y, a.y),
                       __builtin_fmaf(t, b.z - a.z, a.z));
}

__device__ __forceinline__ float3 sample_vpair16(
    const uint2* __restrict__ tab, float px, float py)
{
    float fx = px * GM1F;
    float fy = py * GM1F;
    int ix = (int)fx;             // px in [0,1): ix <= 510, iy <= 510
    int iy = (int)fy;
    float tx = fx - (float)ix;
    float ty = fy - (float)iy;
    uv4 q = *reinterpret_cast<const uv4*>(tab + (iy << 9) + ix);
    // q.x=top(ix) q.y=bot(ix) q.z=top(ix+1) q.w=bot(ix+1)
    float3 c0 = lerp3(unpack_raw(q.x), unpack_raw(q.z), tx);
    float3 c1 = lerp3(unpack_raw(q.y), unpack_raw(q.w), tx);
    float3 r  = lerp3(c0, c1, ty);
    return make_float3(r.x * (1.0f / 2047.0f),
                       r.y * (1.0f / 2047.0f),
                       r.z * (1.0f / 1023.0f));
}

// ---- LUT main pass over group range [t0, t0+tn): 4 px/thread ----
__global__ __launch_bounds__(256) void vpair_b_kernel(
    const float* __restrict__ x, const uint2* __restrict__ tab,
    float* __restrict__ out, int t0, int tn)
{
    int tid = blockIdx.x * blockDim.x + threadIdx.x;
    if (tid >= tn) return;
    int t = t0 + tid;
    const vfloat4* xv = reinterpret_cast<const vfloat4*>(x);
    vfloat4 xa = __builtin_nontemporal_load(&xv[2 * t + 0]);
    vfloat4 xb = __builtin_nontemporal_load(&xv[2 * t + 1]);

    float3 o0 = sample_vpair16(tab, xa.x, xa.y);
    float3 o1 = sample_vpair16(tab, xa.z, xa.w);
    float3 o2 = sample_vpair16(tab, xb.x, xb.y);
    float3 o3 = sample_vpair16(tab, xb.z, xb.w);

    vfloat4 s0 = {o0.x, o0.y, o0.z, o1.x};
    vfloat4 s1 = {o1.y, o1.z, o2.x, o2.y};
    vfloat4 s2 = {o2.z, o3.x, o3.y, o3.z};
    vfloat4* op = reinterpret_cast<vfloat4*>(out);
    __builtin_nontemporal_store(s0, &op[3 * t + 0]);
    __builtin_nontemporal_store(s1, &op[3 * t + 1]);
    __builtin_nontemporal_store(s2, &op[3 * t + 2]);
}

// ---- direct2: exact eval, 2 px/thread, thread range [0, nthreads) ----
__global__ __launch_bounds__(256) void direct2_kernel(
    const float* __restrict__ x,
    const float* __restrict__ Win, const float* __restrict__ Wh,
    const float* __restrict__ Wout, float* __restrict__ out, int nthreads)
{
    int t = blockIdx.x * blockDim.x + threadIdx.x;
    if (t >= nthreads) return;

    // uniform weights -> local static-indexed arrays (compiler: s_load/SGPR)
    float win[16], wh[64], wo[24];
#pragma unroll
    for (int i = 0; i < 16; ++i) win[i] = Win[i];
#pragma unroll
    for (int i = 0; i < 64; ++i) wh[i] = Wh[i];
#pragma unroll
    for (int i = 0; i < 24; ++i) wo[i] = Wout[i];

    const vfloat4* xv = reinterpret_cast<const vfloat4*>(x);
    vfloat4 p = __builtin_nontemporal_load(&xv[t]);   // 2 pixels

    float o0[3], o1[3];
    eval2(p.x, p.y, p.z, p.w, win, wh, wo, o0, o1);

    // 24 B/thread as 3x aligned 8B NT stores (24*t % 8 == 0)
    vfloat2* op = reinterpret_cast<vfloat2*>(out);
    vfloat2 s0 = {o0[0], o0[1]};
    vfloat2 s1 = {o0[2], o1[0]};
    vfloat2 s2 = {o1[1], o1[2]};
    __builtin_nontemporal_store(s0, &op[3 * t + 0]);
    __builtin_nontemporal_store(s1, &op[3 * t + 1]);
    __builtin_nontemporal_store(s2, &op[3 * t + 2]);
}

// ================= fallback: direct evaluation, 4 px/thread =========

__global__ __launch_bounds__(256) void direct_kernel(
    const float* __restrict__ x,
    const float* __restrict__ Win, const float* __restrict__ Wh,
    const float* __restrict__ Wout, float* __restrict__ out, int npix)
{
    int t = blockIdx.x * blockDim.x + threadIdx.x;
    if (t * 4 >= npix) return;
    const float4* xv = reinterpret_cast<const float4*>(x);
    float4 xa = xv[2 * t + 0];
    float4 xb = xv[2 * t + 1];
    float o[4][3];
    net_eval(xa.x, xa.y, Win, Wh, Wout, o[0]);
    net_eval(xa.z, xa.w, Win, Wh, Wout, o[1]);
    net_eval(xb.x, xb.y, Win, Wh, Wout, o[2]);
    net_eval(xb.z, xb.w, Win, Wh, Wout, o[3]);
    float4 s0 = make_float4(o[0][0], o[0][1], o[0][2], o[1][0]);
    float4 s1 = make_float4(o[1][1], o[1][2], o[2][0], o[2][1]);
    float4 s2 = make_float4(o[2][2], o[3][0], o[3][1], o[3][2]);
    float4* op = reinterpret_cast<float4*>(out);
    op[3 * t + 0] = s0;
    op[3 * t + 1] = s1;
    op[3 * t + 2] = s2;
}

extern "C" void kernel_launch(void* const* d_in, const int* in_sizes, int n_in,
                              void* d_out, int out_size, void* d_ws, size_t ws_size,
                              hipStream_t stream) {
    const float* x    = (const float*)d_in[0];
    const float* Win  = (const float*)d_in[1];
    const float* Wh   = (const float*)d_in[2];
    const float* Wout = (const float*)d_in[3];
    float* out = (float*)d_out;

    const int npix = in_sizes[0] / 2;        // 16,777,216
    const int block = 256;

    const size_t pair_bytes = (size_t)G * G * sizeof(uint2);        // 2 MiB
    const size_t tex_bytes  = (size_t)G * G * sizeof(unsigned int); // 1 MiB

    if (ws_size >= pair_bytes + tex_bytes && npix % (16 * block) == 0) {
        uint2* pair = (uint2*)d_ws;
        unsigned int* tex = (unsigned int*)((char*)d_ws + pair_bytes);
        build_tex_kernel<<<(G * G) / block, block, 0, stream>>>(Win, Wh, Wout, tex);
        build_vpair_kernel<<<(G * G) / block, block, 0, stream>>>(tex, pair);

        // half/half A/B: direct2 on pixels [0, npix/2), LUT on the rest
        const int half_px    = npix / 2;         // 8,388,608
        const int d2_threads = half_px / 2;      // 4,194,304 (2 px/thread)
        direct2_kernel<<<d2_threads / block, block, 0, stream>>>(
            x, Win, Wh, Wout, out, d2_threads);

        const int t0 = half_px / 4;              // LUT group start 2,097,152
        const int tn = (npix - half_px) / 4;     // 2,097,152 groups
        vpair_b_kernel<<<tn / block, block, 0, stream>>>(x, pair, out, t0, tn);
    } else {
        const int nthreads = npix / 4;
        direct_kernel<<<(nthreads + block - 1) / block, block, 0, stream>>>(
            x, Win, Wh, Wout, out, npix);
    }
}

// Round 8
// 384.554 us; speedup vs baseline: 1.1497x; 1.1497x over previous
//
#include <hip/hip_runtime.h>
#include <hip/hip_fp16.h>

// Net_55439437857087: per-pixel MLP 2->8->4x(8x8)->3 over 16.7M pixels.
// LUT arc (R3-R10): 512x512 vertical-pair table + bilinear, 2MB ws, main
//   151us. Proven: line-count is the lever (R7), per-request and L1-allocate
//   terms ~0 (R6/R9), ILP pipelining can't beat the per-CU miss-parallelism
//   (MSHR) cap (R10). LUT floor ~150us, memory-latency bound, VALU 15%.
// R11: direct2 (exact fp32, 2px/thread interleaved, weights in SGPRs) on
//   half range = 145us @ VALUBusy 90%, VGPR 16 -> genuinely issue-bound,
//   ~10.6 cy/px/CU (trans-heavy: 86 exp/rcp per px). Direct alone loses
//   (290us full) BUT is resource-complementary to LUT (VALU vs memory).
// R12 (this round): FUSE - one kernel, wave-uniform branch on blockIdx:
//   1/3 of pixels direct (512px/block), 2/3 LUT (1024px/block), parity-
//   interleaved so every CU hosts both wave types. Direct waves fill VALU
//   slots LUT waves leave idle; LUT waves keep memory at MSHR cap.
//   Ideal overlap: max(.333*290, .667*151) ~= 101us main.

#define EXP2F(x) __builtin_amdgcn_exp2f(x)
#define RCPF(x)  __builtin_amdgcn_rcpf(x)

#define G 512
#define GM1F 511.0f

typedef float vfloat4 __attribute__((ext_vector_type(4)));  // nontemporal-compatible
typedef float vfloat2 __attribute__((ext_vector_type(2)));
typedef unsigned int uv4 __attribute__((ext_vector_type(4), aligned(8)));

// ---- single-pixel network eval (build passes + fallback) ----
__device__ __forceinline__ void net_eval(
    float px, float py,
    const float* __restrict__ Win, const float* __restrict__ Wh,
    const float* __restrict__ Wout, float o[3])
{
    const float S  = 2.8853900817779268f;   // 2*log2(e)
    const float SO = -1.4426950408889634f;  // -log2(e)
    float h[8];
#pragma unroll
    for (int j = 0; j < 8; ++j) {
        float acc = __builtin_fmaf(px, Win[2 * j], py * Win[2 * j + 1]);
        h[j] = __builtin_fmaf(-2.0f, RCPF(EXP2F(S * acc) + 1.0f), 1.0f);
    }
#pragma unroll
    for (int L = 0; L < 4; ++L) {
        float nh[8];
#pragma unroll
        for (int j = 0; j < 8; ++j) {
            float acc = 0.0f;
#pragma unroll
            for (int k = 0; k < 8; ++k)
                acc = __builtin_fmaf(h[k], Wh[8 * j + k], acc);
            nh[j] = __builtin_fmaf(-2.0f, RCPF(EXP2F(S * acc) + 1.0f), 1.0f);
        }
#pragma unroll
        for (int j = 0; j < 8; ++j) h[j] = nh[j];
    }
#pragma unroll
    for (int c = 0; c < 3; ++c) {
        float acc = 0.0f;
#pragma unroll
        for (int k = 0; k < 8; ++k)
            acc = __builtin_fmaf(h[k], Wout[8 * c + k], acc);
        o[c] = RCPF(EXP2F(SO * acc) + 1.0f);
    }
}

// ---- two-pixel interleaved eval (explicit ILP; weights pre-cached) ----
__device__ __forceinline__ void eval2(
    float px0, float py0, float px1, float py1,
    const float* __restrict__ win, const float* __restrict__ wh,
    const float* __restrict__ wo, float o0[3], float o1[3])
{
    const float S  = 2.8853900817779268f;   // 2*log2(e)
    const float SO = -1.4426950408889634f;  // -log2(e)
    float h0[8], h1[8];
#pragma unroll
    for (int j = 0; j < 8; ++j) {
        float a0 = __builtin_fmaf(px0, win[2 * j], py0 * win[2 * j + 1]);
        float a1 = __builtin_fmaf(px1, win[2 * j], py1 * win[2 * j + 1]);
        h0[j] = __builtin_fmaf(-2.0f, RCPF(EXP2F(S * a0) + 1.0f), 1.0f);
        h1[j] = __builtin_fmaf(-2.0f, RCPF(EXP2F(S * a1) + 1.0f), 1.0f);
    }
#pragma unroll
    for (int L = 0; L < 4; ++L) {
        float n0[8], n1[8];
#pragma unroll
        for (int j = 0; j < 8; ++j) {
            float a0 = 0.0f, a1 = 0.0f;
#pragma unroll
            for (int k = 0; k < 8; ++k) {
                a0 = __builtin_fmaf(h0[k], wh[8 * j + k], a0);
                a1 = __builtin_fmaf(h1[k], wh[8 * j + k], a1);
            }
            n0[j] = __builtin_fmaf(-2.0f, RCPF(EXP2F(S * a0) + 1.0f), 1.0f);
            n1[j] = __builtin_fmaf(-2.0f, RCPF(EXP2F(S * a1) + 1.0f), 1.0f);
        }
#pragma unroll
        for (int j = 0; j < 8; ++j) { h0[j] = n0[j]; h1[j] = n1[j]; }
    }
#pragma unroll
    for (int c = 0; c < 3; ++c) {
        float a0 = 0.0f, a1 = 0.0f;
#pragma unroll
        for (int k = 0; k < 8; ++k) {
            a0 = __builtin_fmaf(h0[k], wo[8 * c + k], a0);
            a1 = __builtin_fmaf(h1[k], wo[8 * c + k], a1);
        }
        o0[c] = RCPF(EXP2F(SO * a0) + 1.0f);
        o1[c] = RCPF(EXP2F(SO * a1) + 1.0f);
    }
}

// ================= build passes (unchanged) =================

__global__ __launch_bounds__(256) void build_tex_kernel(
    const float* __restrict__ Win, const float* __restrict__ Wh,
    const float* __restrict__ Wout, unsigned int* __restrict__ tex)
{
    int t = blockIdx.x * blockDim.x + threadIdx.x;
    if (t >= G * G) return;
    int i = t & (G - 1);
    int j = t >> 9;               // t / G
    const float inv = 1.0f / GM1F;
    float o[3];
    net_eval(i * inv, j * inv, Win, Wh, Wout, o);
    unsigned int r = (unsigned int)__builtin_rintf(o[0] * 2047.0f);
    unsigned int g = (unsigned int)__builtin_rintf(o[1] * 2047.0f);
    unsigned int b = (unsigned int)__builtin_rintf(o[2] * 1023.0f);
    tex[t] = r | (g << 11) | (b << 22);
}

// Entry (ix,iy): texel(ix,iy) in .x, texel(ix,iy+1) in .y  (vertical pair)
__global__ __launch_bounds__(256) void build_vpair_kernel(
    const unsigned int* __restrict__ tex, uint2* __restrict__ pair)
{
    int t = blockIdx.x * blockDim.x + threadIdx.x;
    if (t >= G * G) return;
    int ix = t & (G - 1);
    int iy = t >> 9;
    int iy1 = min(iy + 1, G - 1);
    uint2 q;
    q.x = tex[iy * G + ix];
    q.y = tex[iy1 * G + ix];
    pair[t] = q;
}

// ================= LUT sampling (bit-identical to R9-B) =================

__device__ __forceinline__ float3 unpack_raw(unsigned int v) {
    return make_float3((float)(v & 2047u),
                       (float)((v >> 11) & 2047u),
                       (float)(v >> 22));
}

__device__ __forceinline__ float3 lerp3(float3 a, float3 b, float t) {
    return make_float3(__builtin_fmaf(t, b.x - a.x, a.x),
                       __builtin_fmaf(t, b.y - a.y, a.y),
                       __builtin_fmaf(t, b.z - a.z, a.z));
}

__device__ __forceinline__ float3 sample_vpair16(
    const uint2* __restrict__ tab, float px, float py)
{
    float fx = px * GM1F;
    float fy = py * GM1F;
    int ix = (int)fx;             // px in [0,1): ix <= 510, iy <= 510
    int iy = (int)fy;
    float tx = fx - (float)ix;
    float ty = fy - (float)iy;
    uv4 q = *reinterpret_cast<const uv4*>(tab + (iy << 9) + ix);
    // q.x=top(ix) q.y=bot(ix) q.z=top(ix+1) q.w=bot(ix+1)
    float3 c0 = lerp3(unpack_raw(q.x), unpack_raw(q.z), tx);
    float3 c1 = lerp3(unpack_raw(q.y), unpack_raw(q.w), tx);
    float3 r  = lerp3(c0, c1, ty);
    return make_float3(r.x * (1.0f / 2047.0f),
                       r.y * (1.0f / 2047.0f),
                       r.z * (1.0f / 1023.0f));
}

// ================= R12 fused main pass =================
// Blocks [0, 2*ND): even -> direct (512 px), odd -> LUT (1024 px).
// Blocks >= 2*ND: LUT (handles NL = ND+1 imbalance).
// Direct pixels occupy [0, ND*512); LUT pixels [ND*512, npix).
__global__ __launch_bounds__(256) void fused_main_kernel(
    const float* __restrict__ x, const uint2* __restrict__ tab,
    const float* __restrict__ Win, const float* __restrict__ Wh,
    const float* __restrict__ Wout, float* __restrict__ out,
    int ND, int lut_t0 /* = ND*128 */)
{
    int b = blockIdx.x;
    int tid = threadIdx.x;
    int twoND = 2 * ND;
    bool is_direct;
    int sub;
    if (b < twoND) { is_direct = ((b & 1) == 0); sub = b >> 1; }
    else           { is_direct = false;          sub = b - ND; }

    if (is_direct) {
        // ---- direct: 2 px/thread, exact fp32 ----
        float win[16], wh[64], wo[24];
#pragma unroll
        for (int i = 0; i < 16; ++i) win[i] = Win[i];
#pragma unroll
        for (int i = 0; i < 64; ++i) wh[i] = Wh[i];
#pragma unroll
        for (int i = 0; i < 24; ++i) wo[i] = Wout[i];

        int g = sub * 256 + tid;                  // 2-px group index
        const vfloat4* xv = reinterpret_cast<const vfloat4*>(x);
        vfloat4 p = __builtin_nontemporal_load(&xv[g]);

        float o0[3], o1[3];
        eval2(p.x, p.y, p.z, p.w, win, wh, wo, o0, o1);

        vfloat2* op = reinterpret_cast<vfloat2*>(out);
        vfloat2 s0 = {o0[0], o0[1]};
        vfloat2 s1 = {o0[2], o1[0]};
        vfloat2 s2 = {o1[1], o1[2]};
        __builtin_nontemporal_store(s0, &op[3 * g + 0]);
        __builtin_nontemporal_store(s1, &op[3 * g + 1]);
        __builtin_nontemporal_store(s2, &op[3 * g + 2]);
    } else {
        // ---- LUT: 4 px/thread (R9-B sampler, bit-identical) ----
        int t = lut_t0 + sub * 256 + tid;         // 4-px group index
        const vfloat4* xv = reinterpret_cast<const vfloat4*>(x);
        vfloat4 xa = __builtin_nontemporal_load(&xv[2 * t + 0]);
        vfloat4 xb = __builtin_nontemporal_load(&xv[2 * t + 1]);

        float3 o0 = sample_vpair16(tab, xa.x, xa.y);
        float3 o1 = sample_vpair16(tab, xa.z, xa.w);
        float3 o2 = sample_vpair16(tab, xb.x, xb.y);
        float3 o3 = sample_vpair16(tab, xb.z, xb.w);

        vfloat4 s0 = {o0.x, o0.y, o0.z, o1.x};
        vfloat4 s1 = {o1.y, o1.z, o2.x, o2.y};
        vfloat4 s2 = {o2.z, o3.x, o3.y, o3.z};
        vfloat4* op = reinterpret_cast<vfloat4*>(out);
        __builtin_nontemporal_store(s0, &op[3 * t + 0]);
        __builtin_nontemporal_store(s1, &op[3 * t + 1]);
        __builtin_nontemporal_store(s2, &op[3 * t + 2]);
    }
}

// ---- LUT-only main pass (fallback), 4 px/thread ----
__global__ __launch_bounds__(256) void vpair_b_kernel(
    const float* __restrict__ x, const uint2* __restrict__ tab,
    float* __restrict__ out, int npix)
{
    int t = blockIdx.x * blockDim.x + threadIdx.x;
    if (t * 4 >= npix) return;
    const vfloat4* xv = reinterpret_cast<const vfloat4*>(x);
    vfloat4 xa = __builtin_nontemporal_load(&xv[2 * t + 0]);
    vfloat4 xb = __builtin_nontemporal_load(&xv[2 * t + 1]);

    float3 o0 = sample_vpair16(tab, xa.x, xa.y);
    float3 o1 = sample_vpair16(tab, xa.z, xa.w);
    float3 o2 = sample_vpair16(tab, xb.x, xb.y);
    float3 o3 = sample_vpair16(tab, xb.z, xb.w);

    vfloat4 s0 = {o0.x, o0.y, o0.z, o1.x};
    vfloat4 s1 = {o1.y, o1.z, o2.x, o2.y};
    vfloat4 s2 = {o2.z, o3.x, o3.y, o3.z};
    vfloat4* op = reinterpret_cast<vfloat4*>(out);
    __builtin_nontemporal_store(s0, &op[3 * t + 0]);
    __builtin_nontemporal_store(s1, &op[3 * t + 1]);
    __builtin_nontemporal_store(s2, &op[3 * t + 2]);
}

// ================= fallback: direct evaluation, 4 px/thread =========

__global__ __launch_bounds__(256) void direct_kernel(
    const float* __restrict__ x,
    const float* __restrict__ Win, const float* __restrict__ Wh,
    const float* __restrict__ Wout, float* __restrict__ out, int npix)
{
    int t = blockIdx.x * blockDim.x + threadIdx.x;
    if (t * 4 >= npix) return;
    const float4* xv = reinterpret_cast<const float4*>(x);
    float4 xa = xv[2 * t + 0];
    float4 xb = xv[2 * t + 1];
    float o[4][3];
    net_eval(xa.x, xa.y, Win, Wh, Wout, o[0]);
    net_eval(xa.z, xa.w, Win, Wh, Wout, o[1]);
    net_eval(xb.x, xb.y, Win, Wh, Wout, o[2]);
    net_eval(xb.z, xb.w, Win, Wh, Wout, o[3]);
    float4 s0 = make_float4(o[0][0], o[0][1], o[0][2], o[1][0]);
    float4 s1 = make_float4(o[1][1], o[1][2], o[2][0], o[2][1]);
    float4 s2 = make_float4(o[2][2], o[3][0], o[3][1], o[3][2]);
    float4* op = reinterpret_cast<float4*>(out);
    op[3 * t + 0] = s0;
    op[3 * t + 1] = s1;
    op[3 * t + 2] = s2;
}

extern "C" void kernel_launch(void* const* d_in, const int* in_sizes, int n_in,
                              void* d_out, int out_size, void* d_ws, size_t ws_size,
                              hipStream_t stream) {
    const float* x    = (const float*)d_in[0];
    const float* Win  = (const float*)d_in[1];
    const float* Wh   = (const float*)d_in[2];
    const float* Wout = (const float*)d_in[3];
    float* out = (float*)d_out;

    const int npix = in_sizes[0] / 2;        // 16,777,216
    const int block = 256;

    const size_t pair_bytes = (size_t)G * G * sizeof(uint2);        // 2 MiB
    const size_t tex_bytes  = (size_t)G * G * sizeof(unsigned int); // 1 MiB

    if (ws_size >= pair_bytes + tex_bytes && npix % 1536 == 0 && npix % 512 == 0) {
        uint2* pair = (uint2*)d_ws;
        unsigned int* tex = (unsigned int*)((char*)d_ws + pair_bytes);
        build_tex_kernel<<<(G * G) / block, block, 0, stream>>>(Win, Wh, Wout, tex);
        build_vpair_kernel<<<(G * G) / block, block, 0, stream>>>(tex, pair);

        // split: ND direct blocks (512 px each) + NL LUT blocks (1024 px)
        // ND even, ND*512 + NL*1024 == npix, ND ~= NL (f_direct = 1/3).
        const int K  = npix / 512;               // 32768
        int ND = 2 * (K / 6);                    // 10922
        int NL = (K - ND) / 2;                   // 10923
        const int lut_t0 = ND * 128;             // first LUT 4-px group
        fused_main_kernel<<<ND + NL, block, 0, stream>>>(
            x, pair, Win, Wh, Wout, out, ND, lut_t0);
    } else if (ws_size >= pair_bytes + tex_bytes) {
        uint2* pair = (uint2*)d_ws;
        unsigned int* tex = (unsigned int*)((char*)d_ws + pair_bytes);
        build_tex_kernel<<<(G * G) / block, block, 0, stream>>>(Win, Wh, Wout, tex);
        build_vpair_kernel<<<(G * G) / block, block, 0, stream>>>(tex, pair);
        const int nthreads = npix / 4;
        vpair_b_kernel<<<(nthreads + block - 1) / block, block, 0, stream>>>(
            x, pair, out, npix);
    } else {
        const int nthreads = npix / 4;
        direct_kernel<<<(nthreads + block - 1) / block, block, 0, stream>>>(
            x, Win, Wh, Wout, out, npix);
    }
}